// Round 2
// baseline (310.799 us; speedup 1.0000x reference)
//
#include <hip/hip_runtime.h>

#define N1 2048
#define N2 32768
#define DD 1024
#define BM 256
#define BN 256
#define BK 64
#define NBM (N1 / BM)   // 8
#define NBN (N2 / BN)   // 128
#define NKEY 2048       // keys per query row = (N2/64)*4

typedef __attribute__((ext_vector_type(8))) __bf16 bf16x8;
typedef __attribute__((ext_vector_type(4))) float  f32x4;

typedef const __attribute__((address_space(1))) void gv_t;
typedef __attribute__((address_space(3))) void       lv_t;

__device__ __forceinline__ void gload16(const void* g, void* l) {
  __builtin_amdgcn_global_load_lds((gv_t*)g, (lv_t*)l, 16, 0, 0);
}

__device__ __forceinline__ unsigned short f2b(float x) {  // RNE f32->bf16
  union { float f; unsigned u; } a; a.f = x;
  unsigned r = a.u + 0x7FFFu + ((a.u >> 16) & 1u);
  return (unsigned short)(r >> 16);
}

__device__ __forceinline__ unsigned ordf(float x) {  // order-preserving f32->u32
  union { float f; unsigned u; } a; a.f = x;
  return a.u ^ ((unsigned)((int)a.u >> 31) | 0x80000000u);
}

// Row-normalize + convert to bf16. One block per row of 1024 floats.
__global__ __launch_bounds__(256) void nrmcvt(const float* __restrict__ src,
                                              unsigned short* __restrict__ dst,
                                              float* __restrict__ invn) {
  const int row = blockIdx.x, t = threadIdx.x;
  const float4* s4 = (const float4*)(src + (size_t)row * DD);
  float4 v = s4[t];
  float ss = v.x * v.x + v.y * v.y + v.z * v.z + v.w * v.w;
  #pragma unroll
  for (int o = 32; o > 0; o >>= 1) ss += __shfl_down(ss, o, 64);
  __shared__ float red[4];
  if ((t & 63) == 0) red[t >> 6] = ss;
  __syncthreads();
  float inv = 1.0f / sqrtf(red[0] + red[1] + red[2] + red[3]);
  ushort4 o4;
  o4.x = f2b(v.x * inv); o4.y = f2b(v.y * inv);
  o4.z = f2b(v.z * inv); o4.w = f2b(v.w * inv);
  ((ushort4*)(dst + (size_t)row * DD))[t] = o4;
  if (invn != nullptr && t == 0) invn[row] = inv;
}

// ---------------- 256x256 8-phase GEMM + fused strip top-4 ----------------
// 8 waves (2M x 4N), per-wave C = 128x64. LDS 128KB: A[buf][h]/B[buf][h]
// half-slots of 128 rows x 64 bf16. A-half keyed on row bit6, B-half on
// row bit5, so quadrant (qm,qn) reads exactly slots A[buf][qm], B[buf][qn].

struct Frags { bf16x8 a[2][4]; bf16x8 b[2][2]; };

template <int BUF, int QM, int QN>
__device__ __forceinline__ Frags phase_load(const char* lds, int lane,
                                            int rlA0, int rlB0) {
  Frags f;
  const char* Ab = lds + (BUF * 2 + QM) * 16384;
  const char* Bb = lds + 65536 + (BUF * 2 + QN) * 16384;
  #pragma unroll
  for (int ks = 0; ks < 2; ++ks) {
    int chs = ((ks * 4 + (lane >> 4)) ^ (lane & 7)) << 4;
    #pragma unroll
    for (int m = 0; m < 4; ++m)
      f.a[ks][m] = *(const bf16x8*)(Ab + (rlA0 + m * 16) * 128 + chs);
    #pragma unroll
    for (int n = 0; n < 2; ++n)
      f.b[ks][n] = *(const bf16x8*)(Bb + (rlB0 + n * 16) * 128 + chs);
  }
  return f;
}

template <int QM, int QN>
__device__ __forceinline__ void phase_mma(const Frags& f, f32x4 (&acc)[8][4]) {
  #pragma unroll
  for (int ks = 0; ks < 2; ++ks)
    #pragma unroll
    for (int m = 0; m < 4; ++m)
      #pragma unroll
      for (int n = 0; n < 2; ++n)
        acc[QM * 4 + m][QN * 2 + n] = __builtin_amdgcn_mfma_f32_16x16x32_bf16(
            f.a[ks][m], f.b[ks][n], acc[QM * 4 + m][QN * 2 + n], 0, 0, 0);
}

#define PH_TAIL(MMA)                                     \
    __builtin_amdgcn_s_barrier();                        \
    asm volatile("s_waitcnt lgkmcnt(0)" ::: "memory");   \
    __builtin_amdgcn_sched_barrier(0);                   \
    __builtin_amdgcn_s_setprio(1);                       \
    MMA;                                                 \
    __builtin_amdgcn_s_setprio(0);                       \
    __builtin_amdgcn_sched_barrier(0);                   \
    __builtin_amdgcn_s_barrier();

__global__ __launch_bounds__(512, 2) void gemm_topk(
    const unsigned short* __restrict__ qb,
    const unsigned short* __restrict__ mbn,
    unsigned* __restrict__ cand_k) {
  __shared__ char lds[131072];
  const int tid = threadIdx.x, lane = tid & 63, w = tid >> 6;
  const int wr = w >> 2, wc = w & 3;

  int bid = blockIdx.x;
  int swz = (bid & 7) * (NBM * NBN / 8) + (bid >> 3);  // 1024 % 8 == 0
  const int bm = swz >> 7;          // NBN == 128
  const int bn = swz & (NBN - 1);

  const char* aG = (const char*)(qb  + (size_t)bm * BM * DD);
  const char* bG = (const char*)(mbn + (size_t)bn * BN * DD);

  // Stage one half-tile (128 rows x 64 bf16 = 16KB): linear LDS dest via
  // global_load_lds, XOR swizzle applied on the GLOBAL source (rule #21).
  auto stageA = [&](int buf, int h, int kt) {
    #pragma unroll
    for (int it = 0; it < 2; ++it) {
      int p = it * 512 + tid;
      int rl = p >> 3, c = p & 7, cs = c ^ (rl & 7);
      int g = (rl & 63) | (h << 6) | ((rl >> 6) << 7);  // bit6-keyed halves
      gload16(aG + (size_t)g * (DD * 2) + kt * (BK * 2) + cs * 16,
              lds + (buf * 2 + h) * 16384 + p * 16);
    }
  };
  auto stageB = [&](int buf, int h, int kt) {
    #pragma unroll
    for (int it = 0; it < 2; ++it) {
      int p = it * 512 + tid;
      int rl = p >> 3, c = p & 7, cs = c ^ (rl & 7);
      int g = (rl & 31) | (h << 5) | ((rl >> 5) << 6);  // bit5-keyed halves
      gload16(bG + (size_t)g * (DD * 2) + kt * (BK * 2) + cs * 16,
              lds + 65536 + (buf * 2 + h) * 16384 + p * 16);
    }
  };

  f32x4 acc[8][4] = {};
  const int rlA0 = (lane & 15) + wr * 64;
  const int rlB0 = (lane & 15) + wc * 32;

  // Prologue: buf0 fully (K-tile 0) + buf1 h0 halves (K-tile 1).
  stageA(0, 0, 0); stageB(0, 0, 0); stageA(0, 1, 0); stageB(0, 1, 0);
  stageA(1, 0, 1); stageB(1, 0, 1);
  asm volatile("s_waitcnt vmcnt(4)" ::: "memory");   // buf0's 8 loads done
  __builtin_amdgcn_s_barrier();

  for (int t = 0; t < 8; ++t) {
    const bool pre = (t < 7);
    const int kt1 = 2 * t + 1, kt2 = 2 * t + 2, kt3 = 2 * t + 3;

    { Frags f = phase_load<0, 0, 0>(lds, lane, rlA0, rlB0);     // P0
      stageA(1, 1, kt1);
      PH_TAIL((phase_mma<0, 0>(f, acc))) }
    { Frags f = phase_load<0, 0, 1>(lds, lane, rlA0, rlB0);     // P1
      stageB(1, 1, kt1);
      PH_TAIL((phase_mma<0, 1>(f, acc))) }
    { Frags f = phase_load<0, 1, 0>(lds, lane, rlA0, rlB0);     // P2
      if (pre) stageA(0, 0, kt2);
      PH_TAIL((phase_mma<1, 0>(f, acc))) }
    { Frags f = phase_load<0, 1, 1>(lds, lane, rlA0, rlB0);     // P3
      if (pre) { stageB(0, 0, kt2);
                 asm volatile("s_waitcnt vmcnt(4)" ::: "memory"); }
      else     { asm volatile("s_waitcnt vmcnt(0)" ::: "memory"); }
      PH_TAIL((phase_mma<1, 1>(f, acc))) }
    { Frags f = phase_load<1, 0, 0>(lds, lane, rlA0, rlB0);     // P4
      if (pre) stageA(0, 1, kt2);
      PH_TAIL((phase_mma<0, 0>(f, acc))) }
    { Frags f = phase_load<1, 0, 1>(lds, lane, rlA0, rlB0);     // P5
      if (pre) stageB(0, 1, kt2);
      PH_TAIL((phase_mma<0, 1>(f, acc))) }
    { Frags f = phase_load<1, 1, 0>(lds, lane, rlA0, rlB0);     // P6
      if (pre) stageA(1, 0, kt3);
      PH_TAIL((phase_mma<1, 0>(f, acc))) }
    { Frags f = phase_load<1, 1, 1>(lds, lane, rlA0, rlB0);     // P7
      if (pre) { stageB(1, 0, kt3);
                 asm volatile("s_waitcnt vmcnt(4)" ::: "memory"); }
      PH_TAIL((phase_mma<1, 1>(f, acc))) }
  }

  // ---- epilogue: two 128-row half passes through LDS, strip top-4 ----
  // Physical float index within a row: col ^ ((lr&15)<<2)  (XOR on bits 2-5
  // of the float index; keeps float4 groups contiguous, writes 2-way free,
  // b128 reads uniform-8 per bank-group).
  for (int half = 0; half < 2; ++half) {
    if (wr == half) {
      float* sc = (float*)lds;
      #pragma unroll
      for (int i = 0; i < 8; ++i)
        #pragma unroll
        for (int q = 0; q < 4; ++q) {
          int lr = i * 16 + (lane >> 4) * 4 + q;
          #pragma unroll
          for (int j = 0; j < 4; ++j) {
            int c = wc * 64 + j * 16 + (lane & 15);
            sc[lr * 256 + (c ^ ((lr & 15) << 2))] = acc[i][j][q];
          }
        }
    }
    __syncthreads();
    {
      const float* sc = (const float*)lds;
      const int lr = tid >> 2, st = tid & 3;
      unsigned k0 = 0, k1 = 0, k2 = 0, k3 = 0;
      #pragma unroll
      for (int k4 = 0; k4 < 16; ++k4) {
        int c0 = st * 64 + k4 * 4;
        f32x4 v = *(const f32x4*)(sc + lr * 256 + (c0 ^ ((lr & 15) << 2)));
        #pragma unroll
        for (int e = 0; e < 4; ++e) {
          unsigned key = (ordf(v[e]) & 0xFFFF8000u) |
                         (unsigned)(bn * BN + c0 + e);
          unsigned b = key, t2;
          t2 = k0 < b ? k0 : b; k0 = k0 < b ? b : k0; b = t2;
          t2 = k1 < b ? k1 : b; k1 = k1 < b ? b : k1; b = t2;
          t2 = k2 < b ? k2 : b; k2 = k2 < b ? b : k2; b = t2;
          k3 = k3 < b ? b : k3;
        }
      }
      int qrow = bm * BM + half * 128 + lr;
      unsigned* dst = cand_k + (size_t)qrow * NKEY + (bn * 4 + st) * 4;
      *(uint4*)dst = make_uint4(k0, k1, k2, k3);
    }
    __syncthreads();
  }
}

// One wave per query row: top-16 of 2048 packed keys, exact fp32 rescore,
// stable top-4, gather synth rows and average.
__global__ __launch_bounds__(256) void finalize(
    const float* __restrict__ q, const float* __restrict__ m,
    const float* __restrict__ synth, const unsigned* __restrict__ cand_k,
    const float* __restrict__ inv_mn, float* __restrict__ out) {
  const int lane = threadIdx.x & 63;
  const int row  = blockIdx.x * 4 + (threadIdx.x >> 6);

  uint4 kk[8];
  const uint4* kp = (const uint4*)(cand_k + (size_t)row * NKEY);
  #pragma unroll
  for (int ii = 0; ii < 8; ++ii) kk[ii] = kp[ii * 64 + lane];

  const float4* qp = (const float4*)(q + (size_t)row * DD);
  float4 qv[4];
  #pragma unroll
  for (int ph = 0; ph < 4; ++ph) qv[ph] = qp[ph * 64 + lane];

  unsigned wk[16];
  #pragma unroll
  for (int it = 0; it < 16; ++it) {
    unsigned lm = 0;
    #pragma unroll
    for (int ii = 0; ii < 8; ++ii) {
      unsigned a = kk[ii].x > kk[ii].y ? kk[ii].x : kk[ii].y;
      unsigned b = kk[ii].z > kk[ii].w ? kk[ii].z : kk[ii].w;
      a = a > b ? a : b;
      lm = lm > a ? lm : a;
    }
    #pragma unroll
    for (int o = 1; o < 64; o <<= 1) {
      unsigned other = (unsigned)__shfl_xor((int)lm, o, 64);
      lm = lm > other ? lm : other;
    }
    wk[it] = lm;
    #pragma unroll
    for (int ii = 0; ii < 8; ++ii) {
      kk[ii].x = kk[ii].x == lm ? 0u : kk[ii].x;
      kk[ii].y = kk[ii].y == lm ? 0u : kk[ii].y;
      kk[ii].z = kk[ii].z == lm ? 0u : kk[ii].z;
      kk[ii].w = kk[ii].w == lm ? 0u : kk[ii].w;
    }
  }

  float cosv[16]; int gidx[16];
  #pragma unroll
  for (int it = 0; it < 16; ++it) {
    int g = (int)(wk[it] & 0x7FFFu);
    gidx[it] = g;
    const float4* mp = (const float4*)(m + (size_t)g * DD);
    float d = 0.f;
    #pragma unroll
    for (int ph = 0; ph < 4; ++ph) {
      float4 mv = mp[ph * 64 + lane];
      d += mv.x * qv[ph].x + mv.y * qv[ph].y + mv.z * qv[ph].z + mv.w * qv[ph].w;
    }
    #pragma unroll
    for (int o = 1; o < 64; o <<= 1) d += __shfl_xor(d, o, 64);
    cosv[it] = d * inv_mn[g];
  }

  int sel[4]; bool used[16] = {};
  #pragma unroll
  for (int s = 0; s < 4; ++s) {
    float bv = -1e30f; int bg = 0x7FFFFFFF; int bj = -1;
    #pragma unroll
    for (int j = 0; j < 16; ++j) {
      bool better = !used[j] && (cosv[j] > bv || (cosv[j] == bv && gidx[j] < bg));
      bv = better ? cosv[j] : bv;
      bg = better ? gidx[j] : bg;
      bj = better ? j : bj;
    }
    sel[s] = bg;
    #pragma unroll
    for (int j = 0; j < 16; ++j) used[j] = used[j] || (j == bj);
  }

  const float4* s0 = (const float4*)(synth + (size_t)sel[0] * DD);
  const float4* s1 = (const float4*)(synth + (size_t)sel[1] * DD);
  const float4* s2 = (const float4*)(synth + (size_t)sel[2] * DD);
  const float4* s3 = (const float4*)(synth + (size_t)sel[3] * DD);
  float4* op = (float4*)(out + (size_t)row * DD);
  #pragma unroll
  for (int ph = 0; ph < 4; ++ph) {
    int ix = ph * 64 + lane;
    float4 a = s0[ix], b = s1[ix], c = s2[ix], d = s3[ix];
    float4 r;
    r.x = (a.x + b.x + c.x + d.x) * 0.25f;
    r.y = (a.y + b.y + c.y + d.y) * 0.25f;
    r.z = (a.z + b.z + c.z + d.z) * 0.25f;
    r.w = (a.w + b.w + c.w + d.w) * 0.25f;
    op[ix] = r;
  }
}

extern "C" void kernel_launch(void* const* d_in, const int* in_sizes, int n_in,
                              void* d_out, int out_size, void* d_ws, size_t ws_size,
                              hipStream_t stream) {
  (void)in_sizes; (void)n_in; (void)out_size; (void)ws_size;
  const float* q = (const float*)d_in[0];
  const float* m = (const float*)d_in[1];
  const float* s = (const float*)d_in[2];
  float* out = (float*)d_out;

  // ws layout: qb 4MB | mb 64MB | inv_mn (at 68MB, 128KB) | cand_k (at 69MB, 16MB)
  char* w = (char*)d_ws;
  unsigned short* qb     = (unsigned short*)w;
  unsigned short* mb     = (unsigned short*)(w + (4ull << 20));
  float*          inv_mn = (float*)(w + (68ull << 20));
  unsigned*       cand_k = (unsigned*)(w + (69ull << 20));

  nrmcvt<<<N1, 256, 0, stream>>>(q, qb, nullptr);
  nrmcvt<<<N2, 256, 0, stream>>>(m, mb, inv_mn);
  gemm_topk<<<NBM * NBN, 512, 0, stream>>>(qb, mb, cand_k);
  finalize<<<N1 / 4, 256, 0, stream>>>(q, m, s, cand_k, inv_mn, out);
}

// Round 3
// 298.495 us; speedup vs baseline: 1.0412x; 1.0412x over previous
//
#include <hip/hip_runtime.h>

#define N1 2048
#define N2 32768
#define DD 1024
#define BM 256
#define BN 256
#define BK 64
#define NBM (N1 / BM)   // 8
#define NBN (N2 / BN)   // 128
#define NKEY 2048       // keys per query row = (N2/64)*4

typedef __attribute__((ext_vector_type(8))) __bf16 bf16x8;
typedef __attribute__((ext_vector_type(4))) float  f32x4;

typedef const __attribute__((address_space(1))) void gv_t;
typedef __attribute__((address_space(3))) void       lv_t;

__device__ __forceinline__ void gload16(const void* g, void* l) {
  __builtin_amdgcn_global_load_lds((gv_t*)g, (lv_t*)l, 16, 0, 0);
}

__device__ __forceinline__ unsigned short f2b(float x) {  // RNE f32->bf16
  union { float f; unsigned u; } a; a.f = x;
  unsigned r = a.u + 0x7FFFu + ((a.u >> 16) & 1u);
  return (unsigned short)(r >> 16);
}

__device__ __forceinline__ unsigned ordf(float x) {  // order-preserving f32->u32
  union { float f; unsigned u; } a; a.f = x;
  return a.u ^ ((unsigned)((int)a.u >> 31) | 0x80000000u);
}

// Row-normalize + convert to bf16. One block per row of 1024 floats.
__global__ __launch_bounds__(256) void nrmcvt(const float* __restrict__ src,
                                              unsigned short* __restrict__ dst,
                                              float* __restrict__ invn) {
  const int row = blockIdx.x, t = threadIdx.x;
  const float4* s4 = (const float4*)(src + (size_t)row * DD);
  float4 v = s4[t];
  float ss = v.x * v.x + v.y * v.y + v.z * v.z + v.w * v.w;
  #pragma unroll
  for (int o = 32; o > 0; o >>= 1) ss += __shfl_down(ss, o, 64);
  __shared__ float red[4];
  if ((t & 63) == 0) red[t >> 6] = ss;
  __syncthreads();
  float inv = 1.0f / sqrtf(red[0] + red[1] + red[2] + red[3]);
  ushort4 o4;
  o4.x = f2b(v.x * inv); o4.y = f2b(v.y * inv);
  o4.z = f2b(v.z * inv); o4.w = f2b(v.w * inv);
  ((ushort4*)(dst + (size_t)row * DD))[t] = o4;
  if (invn != nullptr && t == 0) invn[row] = inv;
}

// ---------------- 256x256 8-phase GEMM + fused strip top-4 ----------------
// 8 waves (2M x 4N), per-wave C = 128x64. Snake quadrant order per buf:
// (0,0)->(0,1)->(1,1)->(1,0); A-frags cached 2 phases, B0 cached 4 phases,
// B1 cached 2 phases -> each LDS fragment read EXACTLY once (48 b128/iter
// per wave vs 96 in R2).

__device__ __forceinline__ void loadA8(bf16x8 (&a)[2][4], const char* Ab,
                                       int rlA0, int lane) {
  #pragma unroll
  for (int ks = 0; ks < 2; ++ks) {
    int chs = ((ks * 4 + (lane >> 4)) ^ (lane & 7)) << 4;
    #pragma unroll
    for (int m = 0; m < 4; ++m)
      a[ks][m] = *(const bf16x8*)(Ab + (rlA0 + m * 16) * 128 + chs);
  }
}

__device__ __forceinline__ void loadB4(bf16x8 (&b)[2][2], const char* Bb,
                                       int rlB0, int lane) {
  #pragma unroll
  for (int ks = 0; ks < 2; ++ks) {
    int chs = ((ks * 4 + (lane >> 4)) ^ (lane & 7)) << 4;
    #pragma unroll
    for (int n = 0; n < 2; ++n)
      b[ks][n] = *(const bf16x8*)(Bb + (rlB0 + n * 16) * 128 + chs);
  }
}

template <int QM, int QN>
__device__ __forceinline__ void mma16(const bf16x8 (&a)[2][4],
                                      const bf16x8 (&b)[2][2],
                                      f32x4 (&acc)[8][4]) {
  #pragma unroll
  for (int ks = 0; ks < 2; ++ks)
    #pragma unroll
    for (int m = 0; m < 4; ++m)
      #pragma unroll
      for (int n = 0; n < 2; ++n)
        acc[QM * 4 + m][QN * 2 + n] = __builtin_amdgcn_mfma_f32_16x16x32_bf16(
            a[ks][m], b[ks][n], acc[QM * 4 + m][QN * 2 + n], 0, 0, 0);
}

#define PH_TAIL(MMA)                                     \
    __builtin_amdgcn_s_barrier();                        \
    asm volatile("s_waitcnt lgkmcnt(0)" ::: "memory");   \
    __builtin_amdgcn_sched_barrier(0);                   \
    __builtin_amdgcn_s_setprio(1);                       \
    MMA;                                                 \
    __builtin_amdgcn_s_setprio(0);                       \
    __builtin_amdgcn_sched_barrier(0);                   \
    __builtin_amdgcn_s_barrier();

__global__ __launch_bounds__(512, 2) void gemm_topk(
    const unsigned short* __restrict__ qb,
    const unsigned short* __restrict__ mbn,
    unsigned* __restrict__ cand_k) {
  __shared__ char lds[131072];
  const int tid = threadIdx.x, lane = tid & 63, w = tid >> 6;
  const int wr = w >> 2, wc = w & 3;

  int bid = blockIdx.x;
  int swz = (bid & 7) * (NBM * NBN / 8) + (bid >> 3);  // 1024 % 8 == 0
  const int bm = swz >> 7;          // NBN == 128
  const int bn = swz & (NBN - 1);

  const char* aG = (const char*)(qb  + (size_t)bm * BM * DD);
  const char* bG = (const char*)(mbn + (size_t)bn * BN * DD);

  // Stage one half-tile (128 rows x 64 bf16 = 16KB): linear LDS dest via
  // global_load_lds, XOR swizzle applied on the GLOBAL source (rule #21).
  auto stageA = [&](int buf, int h, int kt) {
    #pragma unroll
    for (int it = 0; it < 2; ++it) {
      int p = it * 512 + tid;
      int rl = p >> 3, c = p & 7, cs = c ^ (rl & 7);
      int g = (rl & 63) | (h << 6) | ((rl >> 6) << 7);  // bit6-keyed halves
      gload16(aG + (size_t)g * (DD * 2) + kt * (BK * 2) + cs * 16,
              lds + (buf * 2 + h) * 16384 + p * 16);
    }
  };
  auto stageB = [&](int buf, int h, int kt) {
    #pragma unroll
    for (int it = 0; it < 2; ++it) {
      int p = it * 512 + tid;
      int rl = p >> 3, c = p & 7, cs = c ^ (rl & 7);
      int g = (rl & 31) | (h << 5) | ((rl >> 5) << 6);  // bit5-keyed halves
      gload16(bG + (size_t)g * (DD * 2) + kt * (BK * 2) + cs * 16,
              lds + 65536 + (buf * 2 + h) * 16384 + p * 16);
    }
  };

  f32x4 acc[8][4] = {};
  const int rlA0 = (lane & 15) + wr * 64;
  const int rlB0 = (lane & 15) + wc * 32;
  const char* As[4] = { lds,           lds + 16384,
                        lds + 32768,   lds + 49152 };
  const char* Bs[4] = { lds + 65536,   lds + 81920,
                        lds + 98304,   lds + 114688 };

  // Prologue mirrors steady-state issue order (P2..P7 of a virtual t=-1):
  // buf0 fully (kt 0), buf1 A-h0 + B-h1 (kt 1).
  stageA(0, 0, 0); stageB(0, 1, 0); stageA(0, 1, 0); stageB(0, 0, 0);
  stageA(1, 0, 1); stageB(1, 1, 1);
  asm volatile("s_waitcnt vmcnt(4)" ::: "memory");   // buf0's 8 loads done
  __builtin_amdgcn_s_barrier();

  bf16x8 a[2][4], b0[2][2], b1[2][2];

  for (int t = 0; t < 8; ++t) {
    const bool pre = (t < 7);
    const int kt1 = 2 * t + 1, kt2 = 2 * t + 2, kt3 = 2 * t + 3;

    // ---- buf0 (kt = 2t), snake (0,0)(0,1)(1,1)(1,0) ----
    { loadA8(a, As[0], rlA0, lane); loadB4(b0, Bs[0], rlB0, lane);   // P0
      stageA(1, 1, kt1);
      PH_TAIL((mma16<0, 0>(a, b0, acc))) }
    { loadB4(b1, Bs[1], rlB0, lane);                                 // P1
      stageB(1, 0, kt1);
      PH_TAIL((mma16<0, 1>(a, b1, acc))) }
    { loadA8(a, As[1], rlA0, lane);                                  // P2
      if (pre) stageA(0, 0, kt2);
      PH_TAIL((mma16<1, 1>(a, b1, acc))) }
    {                                                                // P3
      if (pre) { stageB(0, 1, kt2);
                 asm volatile("s_waitcnt vmcnt(4)" ::: "memory"); }
      else     { asm volatile("s_waitcnt vmcnt(0)" ::: "memory"); }
      PH_TAIL((mma16<1, 0>(a, b0, acc))) }

    // ---- buf1 (kt = 2t+1) ----
    { loadA8(a, As[2], rlA0, lane); loadB4(b0, Bs[2], rlB0, lane);   // P4
      if (pre) stageA(0, 1, kt2);
      PH_TAIL((mma16<0, 0>(a, b0, acc))) }
    { loadB4(b1, Bs[3], rlB0, lane);                                 // P5
      if (pre) stageB(0, 0, kt2);
      PH_TAIL((mma16<0, 1>(a, b1, acc))) }
    { loadA8(a, As[3], rlA0, lane);                                  // P6
      if (pre) stageA(1, 0, kt3);
      PH_TAIL((mma16<1, 1>(a, b1, acc))) }
    {                                                                // P7
      if (pre) { stageB(1, 1, kt3);
                 asm volatile("s_waitcnt vmcnt(4)" ::: "memory"); }
      PH_TAIL((mma16<1, 0>(a, b0, acc))) }
  }

  // ---- epilogue: two 128-row half passes through LDS, strip top-4 ----
  for (int half = 0; half < 2; ++half) {
    if (wr == half) {
      float* sc = (float*)lds;
      #pragma unroll
      for (int i = 0; i < 8; ++i)
        #pragma unroll
        for (int q = 0; q < 4; ++q) {
          int lr = i * 16 + (lane >> 4) * 4 + q;
          #pragma unroll
          for (int j = 0; j < 4; ++j) {
            int c = wc * 64 + j * 16 + (lane & 15);
            sc[lr * 256 + (c ^ ((lr & 15) << 2))] = acc[i][j][q];
          }
        }
    }
    __syncthreads();
    {
      const float* sc = (const float*)lds;
      const int lr = tid >> 2, st = tid & 3;
      unsigned k0 = 0, k1 = 0, k2 = 0, k3 = 0;
      #pragma unroll
      for (int k4 = 0; k4 < 16; ++k4) {
        int c0 = st * 64 + k4 * 4;
        f32x4 v = *(const f32x4*)(sc + lr * 256 + (c0 ^ ((lr & 15) << 2)));
        #pragma unroll
        for (int e = 0; e < 4; ++e) {
          unsigned key = (ordf(v[e]) & 0xFFFF8000u) |
                         (unsigned)(bn * BN + c0 + e);
          unsigned b = key, t2;
          t2 = k0 < b ? k0 : b; k0 = k0 < b ? b : k0; b = t2;
          t2 = k1 < b ? k1 : b; k1 = k1 < b ? b : k1; b = t2;
          t2 = k2 < b ? k2 : b; k2 = k2 < b ? b : k2; b = t2;
          k3 = k3 < b ? b : k3;
        }
      }
      int qrow = bm * BM + half * 128 + lr;
      unsigned* dst = cand_k + (size_t)qrow * NKEY + (bn * 4 + st) * 4;
      *(uint4*)dst = make_uint4(k0, k1, k2, k3);
    }
    __syncthreads();
  }
}

// One wave per query row: top-16 of 2048 packed keys, exact fp32 rescore,
// stable top-4, gather synth rows and average.
__global__ __launch_bounds__(256) void finalize(
    const float* __restrict__ q, const float* __restrict__ m,
    const float* __restrict__ synth, const unsigned* __restrict__ cand_k,
    const float* __restrict__ inv_mn, float* __restrict__ out) {
  const int lane = threadIdx.x & 63;
  const int row  = blockIdx.x * 4 + (threadIdx.x >> 6);

  uint4 kk[8];
  const uint4* kp = (const uint4*)(cand_k + (size_t)row * NKEY);
  #pragma unroll
  for (int ii = 0; ii < 8; ++ii) kk[ii] = kp[ii * 64 + lane];

  const float4* qp = (const float4*)(q + (size_t)row * DD);
  float4 qv[4];
  #pragma unroll
  for (int ph = 0; ph < 4; ++ph) qv[ph] = qp[ph * 64 + lane];

  unsigned wk[16];
  #pragma unroll
  for (int it = 0; it < 16; ++it) {
    unsigned lm = 0;
    #pragma unroll
    for (int ii = 0; ii < 8; ++ii) {
      unsigned a = kk[ii].x > kk[ii].y ? kk[ii].x : kk[ii].y;
      unsigned b = kk[ii].z > kk[ii].w ? kk[ii].z : kk[ii].w;
      a = a > b ? a : b;
      lm = lm > a ? lm : a;
    }
    #pragma unroll
    for (int o = 1; o < 64; o <<= 1) {
      unsigned other = (unsigned)__shfl_xor((int)lm, o, 64);
      lm = lm > other ? lm : other;
    }
    wk[it] = lm;
    #pragma unroll
    for (int ii = 0; ii < 8; ++ii) {
      kk[ii].x = kk[ii].x == lm ? 0u : kk[ii].x;
      kk[ii].y = kk[ii].y == lm ? 0u : kk[ii].y;
      kk[ii].z = kk[ii].z == lm ? 0u : kk[ii].z;
      kk[ii].w = kk[ii].w == lm ? 0u : kk[ii].w;
    }
  }

  float cosv[16]; int gidx[16];
  #pragma unroll
  for (int it = 0; it < 16; ++it) {
    int g = (int)(wk[it] & 0x7FFFu);
    gidx[it] = g;
    const float4* mp = (const float4*)(m + (size_t)g * DD);
    float d = 0.f;
    #pragma unroll
    for (int ph = 0; ph < 4; ++ph) {
      float4 mv = mp[ph * 64 + lane];
      d += mv.x * qv[ph].x + mv.y * qv[ph].y + mv.z * qv[ph].z + mv.w * qv[ph].w;
    }
    #pragma unroll
    for (int o = 1; o < 64; o <<= 1) d += __shfl_xor(d, o, 64);
    cosv[it] = d * inv_mn[g];
  }

  int sel[4]; bool used[16] = {};
  #pragma unroll
  for (int s = 0; s < 4; ++s) {
    float bv = -1e30f; int bg = 0x7FFFFFFF; int bj = -1;
    #pragma unroll
    for (int j = 0; j < 16; ++j) {
      bool better = !used[j] && (cosv[j] > bv || (cosv[j] == bv && gidx[j] < bg));
      bv = better ? cosv[j] : bv;
      bg = better ? gidx[j] : bg;
      bj = better ? j : bj;
    }
    sel[s] = bg;
    #pragma unroll
    for (int j = 0; j < 16; ++j) used[j] = used[j] || (j == bj);
  }

  const float4* s0 = (const float4*)(synth + (size_t)sel[0] * DD);
  const float4* s1 = (const float4*)(synth + (size_t)sel[1] * DD);
  const float4* s2 = (const float4*)(synth + (size_t)sel[2] * DD);
  const float4* s3 = (const float4*)(synth + (size_t)sel[3] * DD);
  float4* op = (float4*)(out + (size_t)row * DD);
  #pragma unroll
  for (int ph = 0; ph < 4; ++ph) {
    int ix = ph * 64 + lane;
    float4 a = s0[ix], b = s1[ix], c = s2[ix], d = s3[ix];
    float4 r;
    r.x = (a.x + b.x + c.x + d.x) * 0.25f;
    r.y = (a.y + b.y + c.y + d.y) * 0.25f;
    r.z = (a.z + b.z + c.z + d.z) * 0.25f;
    r.w = (a.w + b.w + c.w + d.w) * 0.25f;
    op[ix] = r;
  }
}

extern "C" void kernel_launch(void* const* d_in, const int* in_sizes, int n_in,
                              void* d_out, int out_size, void* d_ws, size_t ws_size,
                              hipStream_t stream) {
  (void)in_sizes; (void)n_in; (void)out_size; (void)ws_size;
  const float* q = (const float*)d_in[0];
  const float* m = (const float*)d_in[1];
  const float* s = (const float*)d_in[2];
  float* out = (float*)d_out;

  // ws layout: qb 4MB | mb 64MB | inv_mn (at 68MB, 128KB) | cand_k (at 69MB, 16MB)
  char* w = (char*)d_ws;
  unsigned short* qb     = (unsigned short*)w;
  unsigned short* mb     = (unsigned short*)(w + (4ull << 20));
  float*          inv_mn = (float*)(w + (68ull << 20));
  unsigned*       cand_k = (unsigned*)(w + (69ull << 20));

  nrmcvt<<<N1, 256, 0, stream>>>(q, qb, nullptr);
  nrmcvt<<<N2, 256, 0, stream>>>(m, mb, inv_mn);
  gemm_topk<<<NBM * NBN, 512, 0, stream>>>(qb, mb, cand_k);
  finalize<<<N1 / 4, 256, 0, stream>>>(q, m, s, cand_k, inv_mn, out);
}

// Round 4
// 176.872 us; speedup vs baseline: 1.7572x; 1.6876x over previous
//
#include <hip/hip_runtime.h>

#define N1 2048
#define N2 32768
#define DD 1024
#define BM 128
#define BN 128
#define BK 128          // fp8 elements per K-tile = 128 B/row (same geometry as R1)
#define NBN (N2 / BN)   // 256
#define NBM (N1 / BM)   // 16
#define KT  (DD / BK)   // 8

typedef __attribute__((ext_vector_type(8))) int   i32x8;
typedef __attribute__((ext_vector_type(4))) int   i32x4;
typedef __attribute__((ext_vector_type(4))) float f32x4;

typedef const __attribute__((address_space(1))) void gv_t;
typedef __attribute__((address_space(3))) void       lv_t;

__device__ __forceinline__ void gload16(const void* g, void* l) {
  __builtin_amdgcn_global_load_lds((gv_t*)g, (lv_t*)l, 16, 0, 0);
}

__device__ __forceinline__ unsigned ordf(float x) {  // order-preserving f32->u32
  union { float f; unsigned u; } a; a.f = x;
  return a.u ^ ((unsigned)((int)a.u >> 31) | 0x80000000u);
}

// Row-normalize + convert to fp8 e4m3 (x16 pre-scale: elements land ~0.5,
// well inside e4m3 range; ranking is scale-invariant, rescore is exact fp32).
__global__ __launch_bounds__(256) void nrmcvt8(const float* __restrict__ src,
                                               unsigned char* __restrict__ dst,
                                               float* __restrict__ invn) {
  const int row = blockIdx.x, t = threadIdx.x;
  const float4* s4 = (const float4*)(src + (size_t)row * DD);
  float4 v = s4[t];
  float ss = v.x * v.x + v.y * v.y + v.z * v.z + v.w * v.w;
  #pragma unroll
  for (int o = 32; o > 0; o >>= 1) ss += __shfl_down(ss, o, 64);
  __shared__ float red[4];
  if ((t & 63) == 0) red[t >> 6] = ss;
  __syncthreads();
  float inv = 1.0f / sqrtf(red[0] + red[1] + red[2] + red[3]);
  float sc = inv * 16.0f;
  int p = 0;
  p = __builtin_amdgcn_cvt_pk_fp8_f32(v.x * sc, v.y * sc, p, false);
  p = __builtin_amdgcn_cvt_pk_fp8_f32(v.z * sc, v.w * sc, p, true);
  ((unsigned*)(dst + (size_t)row * DD))[t] = (unsigned)p;
  if (invn != nullptr && t == 0) invn[row] = inv;
}

// MX-fp8 (unit-scale) MFMA GEMM + fused per-row/per-64col-strip top-4,
// packed as (17-bit ordered score | 15-bit global m-index) keys.
// Control flow identical to R1 (proven); data path fp8 K=128.
__global__ __launch_bounds__(256, 2) void gemm_topk(
    const unsigned char* __restrict__ qb,
    const unsigned char* __restrict__ mbn,
    unsigned* __restrict__ cand_k) {
  __shared__ char lds[65536];  // dbuf staging (2 x (16KB A + 16KB B)) / scores union
  const int tid  = threadIdx.x;
  const int lane = tid & 63;
  const int w = tid >> 6, wr = w >> 1, wc = w & 1;

  // XCD-aware bijective swizzle (grid 4096 % 8 == 0)
  int bid = blockIdx.x;
  int swz = (bid & 7) * (NBM * NBN / 8) + (bid >> 3);
  const int bm = swz >> 8;          // NBN == 256
  const int bn = swz & (NBN - 1);

  const char* aG = (const char*)(qb  + (size_t)bm * BM * DD);
  const char* bG = (const char*)(mbn + (size_t)bn * BN * DD);

  f32x4 acc[4][4] = {};

  // Stage A/B tile kt into buffer d. Linear LDS dest via global_load_lds;
  // XOR swizzle (chunk ^= row&7) applied on the GLOBAL source (rule #21).
  auto stage = [&](int d, int kt) {
    #pragma unroll
    for (int it = 0; it < 4; ++it) {
      int p = it * 256 + tid;
      int r = p >> 3, c = p & 7, cs = c ^ (r & 7);
      gload16(aG + (size_t)r * DD + kt * BK + cs * 16,
              lds + d * 32768 + p * 16);
    }
    #pragma unroll
    for (int it = 0; it < 4; ++it) {
      int p = it * 256 + tid;
      int r = p >> 3, c = p & 7, cs = c ^ (r & 7);
      gload16(bG + (size_t)r * DD + kt * BK + cs * 16,
              lds + d * 32768 + 16384 + p * 16);
    }
  };

  auto compute = [&](int d) {
    const char* Abuf = lds + d * 32768;
    const char* Bbuf = Abuf + 16384;
    // fragment: lane holds row (l&15)+16*i, k-bytes [(l>>4)*32, +32)
    // = swizzled chunks (2g)^(r&7), (2g+1)^(r&7)
    const int g2 = 2 * (lane >> 4);
    i32x8 af[4], bb[4];
    #pragma unroll
    for (int i = 0; i < 4; ++i) {
      int ra = wr * 64 + i * 16 + (lane & 15);
      i32x4 lo = *(const i32x4*)(Abuf + ra * 128 + ((g2 ^ (ra & 7)) * 16));
      i32x4 hi = *(const i32x4*)(Abuf + ra * 128 + (((g2 + 1) ^ (ra & 7)) * 16));
      af[i] = __builtin_shufflevector(lo, hi, 0, 1, 2, 3, 4, 5, 6, 7);
      int rb = wc * 64 + i * 16 + (lane & 15);
      i32x4 blo = *(const i32x4*)(Bbuf + rb * 128 + ((g2 ^ (rb & 7)) * 16));
      i32x4 bhi = *(const i32x4*)(Bbuf + rb * 128 + (((g2 + 1) ^ (rb & 7)) * 16));
      bb[i] = __builtin_shufflevector(blo, bhi, 0, 1, 2, 3, 4, 5, 6, 7);
    }
    #pragma unroll
    for (int i = 0; i < 4; ++i)
      #pragma unroll
      for (int j = 0; j < 4; ++j)
        acc[i][j] = __builtin_amdgcn_mfma_scale_f32_16x16x128_f8f6f4(
            af[i], bb[j], acc[i][j], 0 /*A=e4m3*/, 0 /*B=e4m3*/,
            0, 0x7F7F7F7F, 0, 0x7F7F7F7F /*unit e8m0 scales*/);
  };

  // 2-phase pipeline (R1-proven): issue next-tile loads, compute current,
  // one full drain + barrier per tile (__syncthreads).
  stage(0, 0);
  __syncthreads();
  for (int t = 0; t < KT; ++t) {
    if (t + 1 < KT) stage((t + 1) & 1, t + 1);
    compute(t & 1);
    __syncthreads();
  }

  // ---- epilogue: scores -> LDS (rotated, conflict-free), strip top-4 ----
  float* sc = (float*)lds;
  #pragma unroll
  for (int i = 0; i < 4; ++i)
    #pragma unroll
    for (int j = 0; j < 4; ++j)
      #pragma unroll
      for (int q = 0; q < 4; ++q) {
        int r = wr * 64 + i * 16 + (lane >> 4) * 4 + q;
        int c = wc * 64 + j * 16 + (lane & 15);
        sc[r * 128 + ((c + r) & 127)] = acc[i][j][q];
      }
  __syncthreads();

  // 256 threads = 128 rows x 2 strips of 64 cols. Branchless sorted-insert
  // of packed keys (17-bit score | 15-bit index); scores are x256 of cosine
  // (uniform positive scale -> ranking unchanged).
  const int srow = tid >> 1, strip = tid & 1;
  unsigned k0 = 0, k1 = 0, k2 = 0, k3 = 0;
  for (int i = 0; i < 64; ++i) {
    int c = strip * 64 + i;
    float s = sc[srow * 128 + ((c + srow) & 127)];
    unsigned key = (ordf(s) & 0xFFFF8000u) | (unsigned)(bn * BN + c);
    unsigned b = key, t2;
    t2 = k0 < b ? k0 : b; k0 = k0 < b ? b : k0; b = t2;
    t2 = k1 < b ? k1 : b; k1 = k1 < b ? b : k1; b = t2;
    t2 = k2 < b ? k2 : b; k2 = k2 < b ? b : k2; b = t2;
    k3 = k3 < b ? b : k3;
  }
  unsigned* dst = cand_k + (size_t)(bm * BM + srow) * (NBN * 8) + bn * 8 + strip * 4;
  *(uint4*)dst = make_uint4(k0, k1, k2, k3);
}

// One wave per query row: top-16 of 2048 packed keys, exact fp32 rescore,
// stable top-4, gather synth rows and average.
__global__ __launch_bounds__(256) void finalize(
    const float* __restrict__ q, const float* __restrict__ m,
    const float* __restrict__ synth, const unsigned* __restrict__ cand_k,
    const float* __restrict__ inv_mn, float* __restrict__ out) {
  const int lane = threadIdx.x & 63;
  const int row  = blockIdx.x * 4 + (threadIdx.x >> 6);

  uint4 kk[8];
  const uint4* kp = (const uint4*)(cand_k + (size_t)row * (NBN * 8));
  #pragma unroll
  for (int ii = 0; ii < 8; ++ii) kk[ii] = kp[ii * 64 + lane];

  const float4* qp = (const float4*)(q + (size_t)row * DD);
  float4 qv[4];
  #pragma unroll
  for (int ph = 0; ph < 4; ++ph) qv[ph] = qp[ph * 64 + lane];

  unsigned wk[16];
  #pragma unroll
  for (int it = 0; it < 16; ++it) {
    unsigned lm = 0;
    #pragma unroll
    for (int ii = 0; ii < 8; ++ii) {
      unsigned a = kk[ii].x > kk[ii].y ? kk[ii].x : kk[ii].y;
      unsigned b = kk[ii].z > kk[ii].w ? kk[ii].z : kk[ii].w;
      a = a > b ? a : b;
      lm = lm > a ? lm : a;
    }
    #pragma unroll
    for (int o = 1; o < 64; o <<= 1) {
      unsigned other = (unsigned)__shfl_xor((int)lm, o, 64);
      lm = lm > other ? lm : other;
    }
    wk[it] = lm;
    #pragma unroll
    for (int ii = 0; ii < 8; ++ii) {
      kk[ii].x = kk[ii].x == lm ? 0u : kk[ii].x;
      kk[ii].y = kk[ii].y == lm ? 0u : kk[ii].y;
      kk[ii].z = kk[ii].z == lm ? 0u : kk[ii].z;
      kk[ii].w = kk[ii].w == lm ? 0u : kk[ii].w;
    }
  }

  float cosv[16]; int gidx[16];
  #pragma unroll
  for (int it = 0; it < 16; ++it) {
    int g = (int)(wk[it] & 0x7FFFu);
    gidx[it] = g;
    const float4* mp = (const float4*)(m + (size_t)g * DD);
    float d = 0.f;
    #pragma unroll
    for (int ph = 0; ph < 4; ++ph) {
      float4 mv = mp[ph * 64 + lane];
      d += mv.x * qv[ph].x + mv.y * qv[ph].y + mv.z * qv[ph].z + mv.w * qv[ph].w;
    }
    #pragma unroll
    for (int o = 1; o < 64; o <<= 1) d += __shfl_xor(d, o, 64);
    cosv[it] = d * inv_mn[g];
  }

  int sel[4]; bool used[16] = {};
  #pragma unroll
  for (int s = 0; s < 4; ++s) {
    float bv = -1e30f; int bg = 0x7FFFFFFF; int bj = -1;
    #pragma unroll
    for (int j = 0; j < 16; ++j) {
      bool better = !used[j] && (cosv[j] > bv || (cosv[j] == bv && gidx[j] < bg));
      bv = better ? cosv[j] : bv;
      bg = better ? gidx[j] : bg;
      bj = better ? j : bj;
    }
    sel[s] = bg;
    #pragma unroll
    for (int j = 0; j < 16; ++j) used[j] = used[j] || (j == bj);
  }

  const float4* s0 = (const float4*)(synth + (size_t)sel[0] * DD);
  const float4* s1 = (const float4*)(synth + (size_t)sel[1] * DD);
  const float4* s2 = (const float4*)(synth + (size_t)sel[2] * DD);
  const float4* s3 = (const float4*)(synth + (size_t)sel[3] * DD);
  float4* op = (float4*)(out + (size_t)row * DD);
  #pragma unroll
  for (int ph = 0; ph < 4; ++ph) {
    int ix = ph * 64 + lane;
    float4 a = s0[ix], b = s1[ix], c = s2[ix], d = s3[ix];
    float4 r;
    r.x = (a.x + b.x + c.x + d.x) * 0.25f;
    r.y = (a.y + b.y + c.y + d.y) * 0.25f;
    r.z = (a.z + b.z + c.z + d.z) * 0.25f;
    r.w = (a.w + b.w + c.w + d.w) * 0.25f;
    op[ix] = r;
  }
}

extern "C" void kernel_launch(void* const* d_in, const int* in_sizes, int n_in,
                              void* d_out, int out_size, void* d_ws, size_t ws_size,
                              hipStream_t stream) {
  (void)in_sizes; (void)n_in; (void)out_size; (void)ws_size;
  const float* q = (const float*)d_in[0];
  const float* m = (const float*)d_in[1];
  const float* s = (const float*)d_in[2];
  float* out = (float*)d_out;

  // ws layout: qb 2MB | mb 32MB (at 2MB) | inv_mn (at 40MB) | cand_k (at 41MB, 16MB)
  char* w = (char*)d_ws;
  unsigned char* qb     = (unsigned char*)w;
  unsigned char* mb     = (unsigned char*)(w + (2ull << 20));
  float*         inv_mn = (float*)(w + (40ull << 20));
  unsigned*      cand_k = (unsigned*)(w + (41ull << 20));

  nrmcvt8<<<N1, 256, 0, stream>>>(q, qb, nullptr);
  nrmcvt8<<<N2, 256, 0, stream>>>(m, mb, inv_mn);
  gemm_topk<<<NBM * NBN, 256, 0, stream>>>(qb, mb, cand_k);
  finalize<<<N1 / 4, 256, 0, stream>>>(q, m, s, cand_k, inv_mn, out);
}